// Round 16
// baseline (46.107 us; speedup 1.0000x reference)
//
#include <hip/hip_runtime.h>
#include <hip/hip_bf16.h>

// Forward warp (bilinear splatting), per-tile gather-from-window.
//   img  [B=8, C=3, H=180, W=320] f32
//   flow [B=8, 2,  H=180, W=320] f32
//   scale=4 -> out [B, C, 720, 1280] f32
//
// R16 = champion skeleton at 10x320 tiles to test WRITE DRAM-LOCALITY:
//   write chunks per plane-row are 1280 B (vs 128 B at 40x32) -> much better
//   DRAM page locality for the 88.5 MB output store stream.
//   LDS 38.4 KB -> 4 blocks/CU (16 waves). Window = 21 rows x 26 aligned
//   strips (rows hb-9..hb+11; cols wb-12..wb+91 superset of needed
//   [wb-9,wb+88]; extras provably fail the hit test at |flow|<=8) -> 546
//   strips, 3 items/thread, 15 f32x4 batched unconditional loads.
//   Phase order (load-bearing): zero -> sync -> loads -> predicate+LDS
//   atomics -> sync -> nontemporal exclusive write-out.
// |flow| > 8 pixels go through the EXACT-complement vectorized outlier
// kernel (separate dispatch AFTER tile stores; ordering requires it).

typedef float f32x4 __attribute__((ext_vector_type(4)));

#define B_ 8
#define C_ 3
#define H_ 180
#define W_ 320
#define HW_ (H_ * W_)
#define SCALE_ 4
#define Ho_ (H_ * SCALE_)            // 720
#define Wo_ (W_ * SCALE_)            // 1280
#define TH_ 10
#define TW_ 320
#define NTY_ (Ho_ / TH_)             // 72
#define NTX_ (Wo_ / TW_)             // 4
#define NTILES_ (B_ * NTY_ * NTX_)   // 2304 (divisible by 8 -> bijective XCD swizzle)
#define NPIX_ (B_ * H_ * W_)         // 460800

#define MARGIN_ 8.0f
#define WIN_H_ 21                    // rows hb-9 .. hb+11
#define NSTRIP_W_ 26                 // strips of 4 cols: wb-12 .. wb+91
#define NSTRIPS_ (WIN_H_ * NSTRIP_W_)  // 546 (<= 3*256)
#define ITEMS_PT_ 3
#define PLANE_STRIDE_ 3204           // 3200+4: channel atomics -> distinct banks, 16B-aligned
#define LDS_FLOATS_ (C_ * PLANE_STRIDE_)   // 9612 floats = 38448 B -> 4 blocks/CU

__global__ __launch_bounds__(256) void warp_tile_kernel(const float* __restrict__ img,
                                                        const float* __restrict__ flow,
                                                        float* __restrict__ out) {
    __shared__ __align__(16) float acc[LDS_FLOATS_];
    const int tid = threadIdx.x;

    // XCD-chunked swizzle (2304 % 8 == 0 -> bijective).
    int tile = (int)(blockIdx.x & 7) * (NTILES_ / 8) + (int)(blockIdx.x >> 3);
    const int tx = tile % NTX_;
    const int tt = tile / NTX_;
    const int ty = tt % NTY_;
    const int b  = tt / NTY_;
    const int px0 = tx * TW_;
    const int py0 = ty * TH_;

    for (int j = tid; j < LDS_FLOATS_ / 4; j += 256)
        *reinterpret_cast<f32x4*>(&acc[j * 4]) = (f32x4)(0.f);
    __syncthreads();

    const float* __restrict__ fxp  = flow + (size_t)(b * 2 + 0) * HW_;
    const float* __restrict__ fyp  = flow + (size_t)(b * 2 + 1) * HW_;
    const float* __restrict__ imgb = img + (size_t)b * C_ * HW_;

    const int hb = py0 >> 2;   // floor(py0/4); py0/4 - hb in {0, 0.5} (accounted in WIN_H_)
    const int wb = px0 >> 2;   // 80*tx, exact, 4-aligned

    // ---- phase 1: batched unconditional vector loads (3 strips/thread max) ----
    f32x4 fx4[ITEMS_PT_], fy4[ITEMS_PT_], v04[ITEMS_PT_], v14[ITEMS_PT_], v24[ITEMS_PT_];
    bool av[ITEMS_PT_];
    int h_[ITEMS_PT_], w0_[ITEMS_PT_];
    #pragma unroll
    for (int k = 0; k < ITEMS_PT_; ++k) {
        int si = tid + k * 256;
        int r = si / NSTRIP_W_;
        int s = si - r * NSTRIP_W_;
        int h  = hb - 9 + r;
        int w0 = wb - 12 + 4 * s;
        // strip fully in-row or fully out (w0 % 4 == 0, W % 4 == 0)
        bool act = (si < NSTRIPS_) &&
                   ((unsigned)h < (unsigned)H_) && ((unsigned)w0 < (unsigned)W_);
        av[k] = act; h_[k] = h; w0_[k] = w0;
        int hw = act ? (h * W_ + w0) : 0;
        fx4[k] = *reinterpret_cast<const f32x4*>(&fxp[hw]);
        fy4[k] = *reinterpret_cast<const f32x4*>(&fyp[hw]);
        v04[k] = *reinterpret_cast<const f32x4*>(&imgb[hw]);
        v14[k] = *reinterpret_cast<const f32x4*>(&imgb[HW_ + hw]);
        v24[k] = *reinterpret_cast<const f32x4*>(&imgb[2 * HW_ + hw]);
    }

    // ---- phase 2: predicate + hit-test + LDS accumulate ----
    #pragma unroll
    for (int k = 0; k < ITEMS_PT_; ++k) {
        if (!av[k]) continue;
        #pragma unroll
        for (int j = 0; j < 4; ++j) {
            float fx = fx4[k][j], fy = fy4[k][j];
            // Must be the EXACT complement of outlier_kernel's predicate.
            if (!(fabsf(fx) <= MARGIN_ && fabsf(fy) <= MARGIN_)) continue;

            float x = ((float)(w0_[k] + j) + fx) * (float)SCALE_;
            float y = ((float)h_[k] + fy) * (float)SCALE_;
            float x0f = floorf(x), y0f = floorf(y);
            int ix0 = (int)x0f - px0;   // tile-local
            int iy0 = (int)y0f - py0;
            bool cx0 = (unsigned)ix0 < (unsigned)TW_;
            bool cx1 = (unsigned)(ix0 + 1) < (unsigned)TW_;
            bool cy0 = (unsigned)iy0 < (unsigned)TH_;
            bool cy1 = (unsigned)(iy0 + 1) < (unsigned)TH_;
            if (!((cx0 | cx1) & (cy0 | cy1))) continue;

            float ax = x - x0f, ay = y - y0f;
            float wxs[2] = {1.0f - ax, ax};
            float wys[2] = {1.0f - ay, ay};
            bool cxs[2] = {cx0, cx1};
            bool cys[2] = {cy0, cy1};
            float v0 = v04[k][j], v1 = v14[k][j], v2 = v24[k][j];
            #pragma unroll
            for (int ky = 0; ky < 2; ++ky) {
                if (!cys[ky]) continue;
                #pragma unroll
                for (int kx = 0; kx < 2; ++kx) {
                    if (!cxs[kx]) continue;
                    float wt = wxs[kx] * wys[ky];
                    int la = (iy0 + ky) * TW_ + (ix0 + kx);
                    atomicAdd(&acc[la], v0 * wt);
                    atomicAdd(&acc[la + PLANE_STRIDE_], v1 * wt);
                    atomicAdd(&acc[la + 2 * PLANE_STRIDE_], v2 * wt);
                }
            }
        }
    }
    __syncthreads();

    // ---- phase 3: exclusive nontemporal write-out (1280-B row chunks) ----
    const size_t outb = (size_t)b * C_ * Ho_ * Wo_;
    const size_t chs  = (size_t)Ho_ * Wo_;
    const int F4_PER_PLANE = TH_ * TW_ / 4;        // 800
    const int F4_PER_ROW   = TW_ / 4;              // 80
    for (int j = tid; j < C_ * F4_PER_PLANE; j += 256) {   // 2400 total
        int ch  = j / F4_PER_PLANE;
        int rem = j - ch * F4_PER_PLANE;
        int yy  = rem / F4_PER_ROW;
        int xx4 = rem - yy * F4_PER_ROW;
        f32x4 v = *reinterpret_cast<const f32x4*>(&acc[ch * PLANE_STRIDE_ + yy * TW_ + xx4 * 4]);
        __builtin_nontemporal_store(v,
            reinterpret_cast<f32x4*>(
                &out[outb + (size_t)ch * chs + (size_t)(py0 + yy) * Wo_ + px0 + xx4 * 4]));
    }
}

// Pixels with |flow| > MARGIN_: exact global-atomic splat (AFTER tile writes).
// Vectorized: 4 px/thread via f32x4 flow loads; fast path = all inliers.
__global__ __launch_bounds__(256) void outlier_kernel(const float* __restrict__ img,
                                                      const float* __restrict__ flow,
                                                      float* __restrict__ out) {
    int q = blockIdx.x * 256 + threadIdx.x;   // grid exactly NPIX_/4/256 = 450
    int idx = q * 4;
    int b = idx / HW_;                         // HW_ % 4 == 0 -> same b for all 4
    int hw = idx - b * HW_;
    f32x4 fx4 = *reinterpret_cast<const f32x4*>(&flow[(size_t)(b * 2 + 0) * HW_ + hw]);
    f32x4 fy4 = *reinterpret_cast<const f32x4*>(&flow[(size_t)(b * 2 + 1) * HW_ + hw]);

    bool ol[4];
    bool any = false;
    #pragma unroll
    for (int j = 0; j < 4; ++j) {
        ol[j] = !(fabsf(fx4[j]) <= MARGIN_ && fabsf(fy4[j]) <= MARGIN_);
        any |= ol[j];
    }
    if (!any) return;

    const float* imgb = img + (size_t)b * C_ * HW_;
    const size_t out_b = (size_t)b * C_ * Ho_ * Wo_;
    const size_t chs = (size_t)Ho_ * Wo_;
    #pragma unroll
    for (int j = 0; j < 4; ++j) {
        if (!ol[j]) continue;
        int hwj = hw + j;
        int h = hwj / W_;
        int w = hwj - h * W_;
        float x = ((float)w + fx4[j]) * (float)SCALE_;
        float y = ((float)h + fy4[j]) * (float)SCALE_;
        float x0f = floorf(x), y0f = floorf(y);
        float ax = x - x0f, ay = y - y0f;
        int ix0 = (int)x0f, iy0 = (int)y0f;
        float v0 = imgb[hwj];
        float v1 = imgb[HW_ + hwj];
        float v2 = imgb[2 * HW_ + hwj];
        float wxs[2] = {1.0f - ax, ax};
        float wys[2] = {1.0f - ay, ay};
        #pragma unroll
        for (int ky = 0; ky < 2; ++ky) {
            int yi = iy0 + ky;
            if ((unsigned)yi >= (unsigned)Ho_) continue;
            #pragma unroll
            for (int kx = 0; kx < 2; ++kx) {
                int xi = ix0 + kx;
                if ((unsigned)xi >= (unsigned)Wo_) continue;
                float wt = wxs[kx] * wys[ky];
                size_t base = out_b + (size_t)yi * Wo_ + (size_t)xi;
                atomicAdd(&out[base + 0 * chs], v0 * wt);
                atomicAdd(&out[base + 1 * chs], v1 * wt);
                atomicAdd(&out[base + 2 * chs], v2 * wt);
            }
        }
    }
}

// ---------------- fallback: naive global-atomic splat (scale != 4) ----------------
__global__ __launch_bounds__(256) void splat_naive(const float* __restrict__ img,
                                                   const float* __restrict__ flow,
                                                   const int* __restrict__ scale_p,
                                                   float* __restrict__ out) {
    int idx = blockIdx.x * blockDim.x + threadIdx.x;
    if (idx >= NPIX_) return;
    const int s = *scale_p;
    const int Ho = H_ * s, Wo = W_ * s;
    int w = idx % W_;
    int t = idx / W_;
    int h = t % H_;
    int b = t / H_;
    const int hw = h * W_ + w;
    float fx = flow[((b * 2 + 0) * H_) * W_ + hw];
    float fy = flow[((b * 2 + 1) * H_) * W_ + hw];
    float x = ((float)w + fx) * (float)s;
    float y = ((float)h + fy) * (float)s;
    float x0f = floorf(x), y0f = floorf(y);
    float ax = x - x0f, ay = y - y0f;
    int ix0 = (int)x0f, iy0 = (int)y0f;
    const size_t img_b = (size_t)b * C_ * HW_;
    float v0 = img[img_b + 0 * (size_t)HW_ + hw];
    float v1 = img[img_b + 1 * (size_t)HW_ + hw];
    float v2 = img[img_b + 2 * (size_t)HW_ + hw];
    const size_t out_b = (size_t)b * C_ * Ho * Wo;
    const size_t out_chs = (size_t)Ho * Wo;
    float wxs[2] = {1.0f - ax, ax};
    float wys[2] = {1.0f - ay, ay};
    #pragma unroll
    for (int ky = 0; ky < 2; ++ky) {
        int yi = iy0 + ky;
        if (yi < 0 || yi > Ho - 1) continue;
        #pragma unroll
        for (int kx = 0; kx < 2; ++kx) {
            int xi = ix0 + kx;
            if (xi < 0 || xi > Wo - 1) continue;
            float wt = wxs[kx] * wys[ky];
            size_t base = out_b + (size_t)yi * Wo + (size_t)xi;
            atomicAdd(&out[base + 0 * out_chs], v0 * wt);
            atomicAdd(&out[base + 1 * out_chs], v1 * wt);
            atomicAdd(&out[base + 2 * out_chs], v2 * wt);
        }
    }
}

extern "C" void kernel_launch(void* const* d_in, const int* in_sizes, int n_in,
                              void* d_out, int out_size, void* d_ws, size_t ws_size,
                              hipStream_t stream) {
    const float* img   = (const float*)d_in[0];
    const float* flow  = (const float*)d_in[1];
    const int*   scale = (const int*)d_in[2];
    float* out = (float*)d_out;

    const bool scale4 = (out_size == B_ * C_ * Ho_ * Wo_);

    if (scale4) {
        warp_tile_kernel<<<NTILES_, 256, 0, stream>>>(img, flow, out);
        outlier_kernel<<<NPIX_ / 4 / 256, 256, 0, stream>>>(img, flow, out);
    } else {
        (void)hipMemsetAsync(out, 0, (size_t)out_size * sizeof(float), stream);
        splat_naive<<<(NPIX_ + 255) / 256, 256, 0, stream>>>(img, flow, scale, out);
    }
}

// Round 17
// 44.417 us; speedup vs baseline: 1.0380x; 1.0380x over previous
//
#include <hip/hip_runtime.h>
#include <hip/hip_bf16.h>

// Forward warp (bilinear splatting), per-tile gather-from-window.
//   img  [B=8, C=3, H=180, W=320] f32
//   flow [B=8, 2,  H=180, W=320] f32
//   scale=4 -> out [B, C, 720, 1280] f32
//
// R17 = R14 champion (40x32 tiles, 224 aligned strips, one strip/thread,
// margin 8, max occupancy 32 waves/CU) with ONE change: regular f32x4
// stores instead of nontemporal. Rationale: NT bypasses L2 -> store phase
// pays full HBM latency on the kernel's critical path; regular stores leave
// dirty lines in the 32 MB aggregate L2 that drain lazily, overlapping the
// dispatch tail. Everything else byte-identical to R14.
// |flow| > 8 pixels go through the EXACT-complement vectorized outlier
// kernel (separate dispatch AFTER tile stores; ordering requires it).

typedef float f32x4 __attribute__((ext_vector_type(4)));

#define B_ 8
#define C_ 3
#define H_ 180
#define W_ 320
#define HW_ (H_ * W_)
#define SCALE_ 4
#define Ho_ (H_ * SCALE_)            // 720
#define Wo_ (W_ * SCALE_)            // 1280
#define TH_ 40
#define TW_ 32
#define NTY_ (Ho_ / TH_)             // 18
#define NTX_ (Wo_ / TW_)             // 40
#define NTILES_ (B_ * NTY_ * NTX_)   // 5760 (divisible by 8 -> bijective XCD swizzle)
#define NPIX_ (B_ * H_ * W_)         // 460800

#define MARGIN_ 8.0f
#define WIN_H_ 28                    // rows hb-9 .. hb+18
#define NSTRIP_W_ 8                  // strips of 4 cols: wb-12 .. wb+19
#define NSTRIPS_ (WIN_H_ * NSTRIP_W_)  // 224 (<= 256: one strip per thread)
#define PLANE_STRIDE_ 1284           // 1280+4: channel atomics -> distinct banks, 16B-aligned
#define LDS_FLOATS_ (C_ * PLANE_STRIDE_)   // 3852 floats = 15408 B -> 8 blocks/CU (thread cap)

__global__ __launch_bounds__(256) void warp_tile_kernel(const float* __restrict__ img,
                                                        const float* __restrict__ flow,
                                                        float* __restrict__ out) {
    __shared__ __align__(16) float acc[LDS_FLOATS_];
    const int tid = threadIdx.x;

    // XCD-chunked swizzle (5760 % 8 == 0 -> bijective).
    int tile = (int)(blockIdx.x & 7) * (NTILES_ / 8) + (int)(blockIdx.x >> 3);
    const int tx = tile % NTX_;
    const int tt = tile / NTX_;
    const int ty = tt % NTY_;
    const int b  = tt / NTY_;
    const int px0 = tx * TW_;
    const int py0 = ty * TH_;

    for (int j = tid; j < LDS_FLOATS_ / 4; j += 256)
        *reinterpret_cast<f32x4*>(&acc[j * 4]) = (f32x4)(0.f);
    __syncthreads();

    const float* __restrict__ fxp  = flow + (size_t)(b * 2 + 0) * HW_;
    const float* __restrict__ fyp  = flow + (size_t)(b * 2 + 1) * HW_;
    const float* __restrict__ imgb = img + (size_t)b * C_ * HW_;

    const int hb = py0 >> 2;   // 10*ty
    const int wb = px0 >> 2;   // 8*tx (multiple of 8 -> strips 4-aligned)

    // ---- phase 1: one aligned 4-px strip per thread, 5 f32x4 batched loads ----
    const int r  = tid / NSTRIP_W_;
    const int s  = tid - r * NSTRIP_W_;
    const int h  = hb - 9 + r;
    const int w0 = wb - 12 + 4 * s;
    // strip fully in-row or fully out (w0 % 4 == 0, W % 4 == 0)
    const bool act = (tid < NSTRIPS_) &&
                     ((unsigned)h < (unsigned)H_) && ((unsigned)w0 < (unsigned)W_);
    const int hw = act ? (h * W_ + w0) : 0;
    f32x4 fx4 = *reinterpret_cast<const f32x4*>(&fxp[hw]);
    f32x4 fy4 = *reinterpret_cast<const f32x4*>(&fyp[hw]);
    f32x4 v04 = *reinterpret_cast<const f32x4*>(&imgb[hw]);
    f32x4 v14 = *reinterpret_cast<const f32x4*>(&imgb[HW_ + hw]);
    f32x4 v24 = *reinterpret_cast<const f32x4*>(&imgb[2 * HW_ + hw]);

    // ---- phase 2: predicate + hit-test + LDS accumulate ----
    if (act) {
        #pragma unroll
        for (int j = 0; j < 4; ++j) {
            float fx = fx4[j], fy = fy4[j];
            // Must be the EXACT complement of outlier_kernel's predicate.
            if (!(fabsf(fx) <= MARGIN_ && fabsf(fy) <= MARGIN_)) continue;

            float x = ((float)(w0 + j) + fx) * (float)SCALE_;
            float y = ((float)h + fy) * (float)SCALE_;
            float x0f = floorf(x), y0f = floorf(y);
            int ix0 = (int)x0f - px0;   // tile-local
            int iy0 = (int)y0f - py0;
            bool cx0 = (unsigned)ix0 < (unsigned)TW_;
            bool cx1 = (unsigned)(ix0 + 1) < (unsigned)TW_;
            bool cy0 = (unsigned)iy0 < (unsigned)TH_;
            bool cy1 = (unsigned)(iy0 + 1) < (unsigned)TH_;
            if (!((cx0 | cx1) & (cy0 | cy1))) continue;

            float ax = x - x0f, ay = y - y0f;
            float wxs[2] = {1.0f - ax, ax};
            float wys[2] = {1.0f - ay, ay};
            bool cxs[2] = {cx0, cx1};
            bool cys[2] = {cy0, cy1};
            float v0 = v04[j], v1 = v14[j], v2 = v24[j];
            #pragma unroll
            for (int ky = 0; ky < 2; ++ky) {
                if (!cys[ky]) continue;
                #pragma unroll
                for (int kx = 0; kx < 2; ++kx) {
                    if (!cxs[kx]) continue;
                    float wt = wxs[kx] * wys[ky];
                    int la = (iy0 + ky) * TW_ + (ix0 + kx);
                    atomicAdd(&acc[la], v0 * wt);
                    atomicAdd(&acc[la + PLANE_STRIDE_], v1 * wt);
                    atomicAdd(&acc[la + 2 * PLANE_STRIDE_], v2 * wt);
                }
            }
        }
    }
    __syncthreads();

    // ---- phase 3: exclusive coalesced REGULAR f32x4 write-out (via L2) ----
    const size_t outb = (size_t)b * C_ * Ho_ * Wo_;
    const size_t chs  = (size_t)Ho_ * Wo_;
    const int F4_PER_PLANE = TH_ * TW_ / 4;        // 320
    const int F4_PER_ROW   = TW_ / 4;              // 8
    #pragma unroll
    for (int j = tid; j < C_ * F4_PER_PLANE; j += 256) {   // 960 total, <=4 iters
        int ch  = j / F4_PER_PLANE;
        int rem = j - ch * F4_PER_PLANE;
        int yy  = rem / F4_PER_ROW;
        int xx4 = rem - yy * F4_PER_ROW;
        f32x4 v = *reinterpret_cast<const f32x4*>(&acc[ch * PLANE_STRIDE_ + yy * TW_ + xx4 * 4]);
        *reinterpret_cast<f32x4*>(
            &out[outb + (size_t)ch * chs + (size_t)(py0 + yy) * Wo_ + px0 + xx4 * 4]) = v;
    }
}

// Pixels with |flow| > MARGIN_: exact global-atomic splat (AFTER tile writes).
// Vectorized: 4 px/thread via f32x4 flow loads; fast path = all inliers.
__global__ __launch_bounds__(256) void outlier_kernel(const float* __restrict__ img,
                                                      const float* __restrict__ flow,
                                                      float* __restrict__ out) {
    int q = blockIdx.x * 256 + threadIdx.x;   // grid exactly NPIX_/4/256 = 450
    int idx = q * 4;
    int b = idx / HW_;                         // HW_ % 4 == 0 -> same b for all 4
    int hw = idx - b * HW_;
    f32x4 fx4 = *reinterpret_cast<const f32x4*>(&flow[(size_t)(b * 2 + 0) * HW_ + hw]);
    f32x4 fy4 = *reinterpret_cast<const f32x4*>(&flow[(size_t)(b * 2 + 1) * HW_ + hw]);

    bool ol[4];
    bool any = false;
    #pragma unroll
    for (int j = 0; j < 4; ++j) {
        ol[j] = !(fabsf(fx4[j]) <= MARGIN_ && fabsf(fy4[j]) <= MARGIN_);
        any |= ol[j];
    }
    if (!any) return;

    const float* imgb = img + (size_t)b * C_ * HW_;
    const size_t out_b = (size_t)b * C_ * Ho_ * Wo_;
    const size_t chs = (size_t)Ho_ * Wo_;
    #pragma unroll
    for (int j = 0; j < 4; ++j) {
        if (!ol[j]) continue;
        int hwj = hw + j;
        int h = hwj / W_;
        int w = hwj - h * W_;
        float x = ((float)w + fx4[j]) * (float)SCALE_;
        float y = ((float)h + fy4[j]) * (float)SCALE_;
        float x0f = floorf(x), y0f = floorf(y);
        float ax = x - x0f, ay = y - y0f;
        int ix0 = (int)x0f, iy0 = (int)y0f;
        float v0 = imgb[hwj];
        float v1 = imgb[HW_ + hwj];
        float v2 = imgb[2 * HW_ + hwj];
        float wxs[2] = {1.0f - ax, ax};
        float wys[2] = {1.0f - ay, ay};
        #pragma unroll
        for (int ky = 0; ky < 2; ++ky) {
            int yi = iy0 + ky;
            if ((unsigned)yi >= (unsigned)Ho_) continue;
            #pragma unroll
            for (int kx = 0; kx < 2; ++kx) {
                int xi = ix0 + kx;
                if ((unsigned)xi >= (unsigned)Wo_) continue;
                float wt = wxs[kx] * wys[ky];
                size_t base = out_b + (size_t)yi * Wo_ + (size_t)xi;
                atomicAdd(&out[base + 0 * chs], v0 * wt);
                atomicAdd(&out[base + 1 * chs], v1 * wt);
                atomicAdd(&out[base + 2 * chs], v2 * wt);
            }
        }
    }
}

// ---------------- fallback: naive global-atomic splat (scale != 4) ----------------
__global__ __launch_bounds__(256) void splat_naive(const float* __restrict__ img,
                                                   const float* __restrict__ flow,
                                                   const int* __restrict__ scale_p,
                                                   float* __restrict__ out) {
    int idx = blockIdx.x * blockDim.x + threadIdx.x;
    if (idx >= NPIX_) return;
    const int s = *scale_p;
    const int Ho = H_ * s, Wo = W_ * s;
    int w = idx % W_;
    int t = idx / W_;
    int h = t % H_;
    int b = t / H_;
    const int hw = h * W_ + w;
    float fx = flow[((b * 2 + 0) * H_) * W_ + hw];
    float fy = flow[((b * 2 + 1) * H_) * W_ + hw];
    float x = ((float)w + fx) * (float)s;
    float y = ((float)h + fy) * (float)s;
    float x0f = floorf(x), y0f = floorf(y);
    float ax = x - x0f, ay = y - y0f;
    int ix0 = (int)x0f, iy0 = (int)y0f;
    const size_t img_b = (size_t)b * C_ * HW_;
    float v0 = img[img_b + 0 * (size_t)HW_ + hw];
    float v1 = img[img_b + 1 * (size_t)HW_ + hw];
    float v2 = img[img_b + 2 * (size_t)HW_ + hw];
    const size_t out_b = (size_t)b * C_ * Ho * Wo;
    const size_t out_chs = (size_t)Ho * Wo;
    float wxs[2] = {1.0f - ax, ax};
    float wys[2] = {1.0f - ay, ay};
    #pragma unroll
    for (int ky = 0; ky < 2; ++ky) {
        int yi = iy0 + ky;
        if (yi < 0 || yi > Ho - 1) continue;
        #pragma unroll
        for (int kx = 0; kx < 2; ++kx) {
            int xi = ix0 + kx;
            if (xi < 0 || xi > Wo - 1) continue;
            float wt = wxs[kx] * wys[ky];
            size_t base = out_b + (size_t)yi * Wo + (size_t)xi;
            atomicAdd(&out[base + 0 * out_chs], v0 * wt);
            atomicAdd(&out[base + 1 * out_chs], v1 * wt);
            atomicAdd(&out[base + 2 * out_chs], v2 * wt);
        }
    }
}

extern "C" void kernel_launch(void* const* d_in, const int* in_sizes, int n_in,
                              void* d_out, int out_size, void* d_ws, size_t ws_size,
                              hipStream_t stream) {
    const float* img   = (const float*)d_in[0];
    const float* flow  = (const float*)d_in[1];
    const int*   scale = (const int*)d_in[2];
    float* out = (float*)d_out;

    const bool scale4 = (out_size == B_ * C_ * Ho_ * Wo_);

    if (scale4) {
        warp_tile_kernel<<<NTILES_, 256, 0, stream>>>(img, flow, out);
        outlier_kernel<<<NPIX_ / 4 / 256, 256, 0, stream>>>(img, flow, out);
    } else {
        (void)hipMemsetAsync(out, 0, (size_t)out_size * sizeof(float), stream);
        splat_naive<<<(NPIX_ + 255) / 256, 256, 0, stream>>>(img, flow, scale, out);
    }
}

// Round 18
// 43.779 us; speedup vs baseline: 1.0532x; 1.0146x over previous
//
#include <hip/hip_runtime.h>
#include <hip/hip_bf16.h>

// Forward warp (bilinear splatting), collect-first + per-tile gather.
//   img  [B=8, C=3, H=180, W=320] f32
//   flow [B=8, 2,  H=180, W=320] f32
//   scale=4 -> out [B, C, 720, 1280] f32
//
// R18: two dispatches, reordered:
//  1) collect_kernel (456 blocks): reads flow (+touches img to warm per-XCD
//     L2 with the SAME batch<->XCD mapping the tile kernel uses), compacts
//     |flow|>8 outlier pixel indices into per-block ws regions (capacity =
//     block pixel count -> can never overflow; exact for ANY input).
//  2) warp_tile_kernel (R14 champion: 40x32 tiles, one aligned strip/thread,
//     margin 8, NT stores): accumulates its window inliers into LDS, then
//     MERGES same-batch outlier records whose corners land in this tile into
//     LDS, then one exclusive nontemporal store. No post-store atomics ->
//     no ordering hazard, no third dispatch.
// ws layout: counts u32[456] | records u32[456*1024]  (~1.87 MB)

typedef float f32x4 __attribute__((ext_vector_type(4)));

#define B_ 8
#define C_ 3
#define H_ 180
#define W_ 320
#define HW_ (H_ * W_)                // 57600
#define SCALE_ 4
#define Ho_ (H_ * SCALE_)            // 720
#define Wo_ (W_ * SCALE_)            // 1280
#define TH_ 40
#define TW_ 32
#define NTY_ (Ho_ / TH_)             // 18
#define NTX_ (Wo_ / TW_)             // 40
#define NTILES_ (B_ * NTY_ * NTX_)   // 5760 (divisible by 8 -> bijective XCD swizzle)
#define NPIX_ (B_ * H_ * W_)         // 460800

#define MARGIN_ 8.0f
#define WIN_H_ 28                    // rows hb-9 .. hb+18
#define NSTRIP_W_ 8                  // strips of 4 cols: wb-12 .. wb+19
#define NSTRIPS_ (WIN_H_ * NSTRIP_W_)  // 224 (<= 256: one strip per thread)
#define PLANE_STRIDE_ 1284           // 1280+4: channel atomics -> distinct banks, 16B-aligned
#define LDS_FLOATS_ (C_ * PLANE_STRIDE_)   // 3852 floats = 15408 B -> 8 blocks/CU

#define NREG_ 456                    // collect blocks: 57 chunks x 8 batches
#define REG_CAP_ 1024                // pixels per collect block (= capacity, no overflow)

// ---------------- pass 1: outlier collect + L2 warm ----------------
__global__ __launch_bounds__(256) void collect_kernel(const float* __restrict__ img,
                                                      const float* __restrict__ flow,
                                                      unsigned* __restrict__ counts,
                                                      unsigned* __restrict__ records) {
    __shared__ unsigned cnt;
    const int tid = threadIdx.x;
    const int gb  = blockIdx.x;          // region id
    const int b   = gb & 7;              // batch <-> XCD mapping (matches tile kernel)
    const int chunk = gb >> 3;           // 0..56
    if (tid == 0) cnt = 0;
    __syncthreads();

    const int p = chunk * REG_CAP_ + tid * 4;     // within-batch pixel index, 4-aligned
    const bool act = p < HW_;
    const int hw = act ? p : 0;

    const float* __restrict__ fxp  = flow + (size_t)(b * 2 + 0) * HW_;
    const float* __restrict__ fyp  = flow + (size_t)(b * 2 + 1) * HW_;
    const float* __restrict__ imgb = img + (size_t)b * C_ * HW_;

    f32x4 fx4 = *reinterpret_cast<const f32x4*>(&fxp[hw]);
    f32x4 fy4 = *reinterpret_cast<const f32x4*>(&fyp[hw]);
    // L2-warm img on this XCD; keep loads alive without side effects.
    f32x4 w0 = *reinterpret_cast<const f32x4*>(&imgb[hw]);
    f32x4 w1 = *reinterpret_cast<const f32x4*>(&imgb[HW_ + hw]);
    f32x4 w2 = *reinterpret_cast<const f32x4*>(&imgb[2 * HW_ + hw]);
    float keep = w0[0] + w0[1] + w0[2] + w0[3] + w1[0] + w1[1] + w1[2] + w1[3] +
                 w2[0] + w2[1] + w2[2] + w2[3];
    asm volatile("" :: "v"(keep));

    #pragma unroll
    for (int j = 0; j < 4; ++j) {
        bool ol = act && !(fabsf(fx4[j]) <= MARGIN_ && fabsf(fy4[j]) <= MARGIN_);
        if (ol) {
            unsigned slot = atomicAdd(&cnt, 1u);
            records[(size_t)gb * REG_CAP_ + slot] = (unsigned)(p + j);
        }
    }
    __syncthreads();
    if (tid == 0) counts[gb] = cnt;
}

// ---------------- pass 2: tile gather + outlier merge + exclusive store ----------------
__global__ __launch_bounds__(256) void warp_tile_kernel(const float* __restrict__ img,
                                                        const float* __restrict__ flow,
                                                        const unsigned* __restrict__ counts,
                                                        const unsigned* __restrict__ records,
                                                        float* __restrict__ out) {
    __shared__ __align__(16) float acc[LDS_FLOATS_];
    const int tid = threadIdx.x;

    // XCD-chunked swizzle (5760 % 8 == 0 -> bijective); batch b lands on XCD b.
    int tile = (int)(blockIdx.x & 7) * (NTILES_ / 8) + (int)(blockIdx.x >> 3);
    const int tx = tile % NTX_;
    const int tt = tile / NTX_;
    const int ty = tt % NTY_;
    const int b  = tt / NTY_;
    const int px0 = tx * TW_;
    const int py0 = ty * TH_;

    for (int j = tid; j < LDS_FLOATS_ / 4; j += 256)
        *reinterpret_cast<f32x4*>(&acc[j * 4]) = (f32x4)(0.f);
    __syncthreads();

    const float* __restrict__ fxp  = flow + (size_t)(b * 2 + 0) * HW_;
    const float* __restrict__ fyp  = flow + (size_t)(b * 2 + 1) * HW_;
    const float* __restrict__ imgb = img + (size_t)b * C_ * HW_;

    const int hb = py0 >> 2;
    const int wb = px0 >> 2;

    // ---- phase 1: one aligned 4-px strip per thread, 5 f32x4 batched loads ----
    const int r  = tid / NSTRIP_W_;
    const int s  = tid - r * NSTRIP_W_;
    const int h  = hb - 9 + r;
    const int w0 = wb - 12 + 4 * s;
    const bool act = (tid < NSTRIPS_) &&
                     ((unsigned)h < (unsigned)H_) && ((unsigned)w0 < (unsigned)W_);
    const int hw = act ? (h * W_ + w0) : 0;
    f32x4 fx4 = *reinterpret_cast<const f32x4*>(&fxp[hw]);
    f32x4 fy4 = *reinterpret_cast<const f32x4*>(&fyp[hw]);
    f32x4 v04 = *reinterpret_cast<const f32x4*>(&imgb[hw]);
    f32x4 v14 = *reinterpret_cast<const f32x4*>(&imgb[HW_ + hw]);
    f32x4 v24 = *reinterpret_cast<const f32x4*>(&imgb[2 * HW_ + hw]);

    // ---- phase 2: predicate + hit-test + LDS accumulate (inliers) ----
    if (act) {
        #pragma unroll
        for (int j = 0; j < 4; ++j) {
            float fx = fx4[j], fy = fy4[j];
            // EXACT complement of collect_kernel's outlier predicate.
            if (!(fabsf(fx) <= MARGIN_ && fabsf(fy) <= MARGIN_)) continue;

            float x = ((float)(w0 + j) + fx) * (float)SCALE_;
            float y = ((float)h + fy) * (float)SCALE_;
            float x0f = floorf(x), y0f = floorf(y);
            int ix0 = (int)x0f - px0;   // tile-local
            int iy0 = (int)y0f - py0;
            bool cx0 = (unsigned)ix0 < (unsigned)TW_;
            bool cx1 = (unsigned)(ix0 + 1) < (unsigned)TW_;
            bool cy0 = (unsigned)iy0 < (unsigned)TH_;
            bool cy1 = (unsigned)(iy0 + 1) < (unsigned)TH_;
            if (!((cx0 | cx1) & (cy0 | cy1))) continue;

            float ax = x - x0f, ay = y - y0f;
            float wxs[2] = {1.0f - ax, ax};
            float wys[2] = {1.0f - ay, ay};
            bool cxs[2] = {cx0, cx1};
            bool cys[2] = {cy0, cy1};
            float v0 = v04[j], v1 = v14[j], v2 = v24[j];
            #pragma unroll
            for (int ky = 0; ky < 2; ++ky) {
                if (!cys[ky]) continue;
                #pragma unroll
                for (int kx = 0; kx < 2; ++kx) {
                    if (!cxs[kx]) continue;
                    float wt = wxs[kx] * wys[ky];
                    int la = (iy0 + ky) * TW_ + (ix0 + kx);
                    atomicAdd(&acc[la], v0 * wt);
                    atomicAdd(&acc[la + PLANE_STRIDE_], v1 * wt);
                    atomicAdd(&acc[la + 2 * PLANE_STRIDE_], v2 * wt);
                }
            }
        }
    }

    // ---- phase 2b: merge same-batch outliers whose corners land in this tile ----
    if (counts) {
        for (int g = b + 8 * tid; g < NREG_; g += 8 * 256) {   // only regions of batch b
            unsigned cnt = counts[g];
            for (unsigned i = 0; i < cnt; ++i) {
                unsigned p = records[(size_t)g * REG_CAP_ + i];
                int hh = (int)p / W_;
                int ww = (int)p - hh * W_;
                float fx = fxp[p], fy = fyp[p];
                float x = ((float)ww + fx) * (float)SCALE_;
                float y = ((float)hh + fy) * (float)SCALE_;
                float x0f = floorf(x), y0f = floorf(y);
                int ix0 = (int)x0f - px0;
                int iy0 = (int)y0f - py0;
                bool cx0 = (unsigned)ix0 < (unsigned)TW_;
                bool cx1 = (unsigned)(ix0 + 1) < (unsigned)TW_;
                bool cy0 = (unsigned)iy0 < (unsigned)TH_;
                bool cy1 = (unsigned)(iy0 + 1) < (unsigned)TH_;
                if (!((cx0 | cx1) & (cy0 | cy1))) continue;
                float ax = x - x0f, ay = y - y0f;
                float wxs[2] = {1.0f - ax, ax};
                float wys[2] = {1.0f - ay, ay};
                bool cxs[2] = {cx0, cx1};
                bool cys[2] = {cy0, cy1};
                float v0 = imgb[p], v1 = imgb[HW_ + p], v2 = imgb[2 * HW_ + p];
                #pragma unroll
                for (int ky = 0; ky < 2; ++ky) {
                    if (!cys[ky]) continue;
                    #pragma unroll
                    for (int kx = 0; kx < 2; ++kx) {
                        if (!cxs[kx]) continue;
                        float wt = wxs[kx] * wys[ky];
                        int la = (iy0 + ky) * TW_ + (ix0 + kx);
                        atomicAdd(&acc[la], v0 * wt);
                        atomicAdd(&acc[la + PLANE_STRIDE_], v1 * wt);
                        atomicAdd(&acc[la + 2 * PLANE_STRIDE_], v2 * wt);
                    }
                }
            }
        }
    }
    __syncthreads();

    // ---- phase 3: exclusive coalesced nontemporal write-out ----
    const size_t outb = (size_t)b * C_ * Ho_ * Wo_;
    const size_t chs  = (size_t)Ho_ * Wo_;
    const int F4_PER_PLANE = TH_ * TW_ / 4;        // 320
    const int F4_PER_ROW   = TW_ / 4;              // 8
    #pragma unroll
    for (int j = tid; j < C_ * F4_PER_PLANE; j += 256) {   // 960 total, <=4 iters
        int ch  = j / F4_PER_PLANE;
        int rem = j - ch * F4_PER_PLANE;
        int yy  = rem / F4_PER_ROW;
        int xx4 = rem - yy * F4_PER_ROW;
        f32x4 v = *reinterpret_cast<const f32x4*>(&acc[ch * PLANE_STRIDE_ + yy * TW_ + xx4 * 4]);
        __builtin_nontemporal_store(v,
            reinterpret_cast<f32x4*>(
                &out[outb + (size_t)ch * chs + (size_t)(py0 + yy) * Wo_ + px0 + xx4 * 4]));
    }
}

// Fallback outlier pass (champion path, used when ws is too small):
// global atomics AFTER tile stores. EXACT complement predicate.
__global__ __launch_bounds__(256) void outlier_kernel(const float* __restrict__ img,
                                                      const float* __restrict__ flow,
                                                      float* __restrict__ out) {
    int q = blockIdx.x * 256 + threadIdx.x;
    int idx = q * 4;
    int b = idx / HW_;
    int hw = idx - b * HW_;
    f32x4 fx4 = *reinterpret_cast<const f32x4*>(&flow[(size_t)(b * 2 + 0) * HW_ + hw]);
    f32x4 fy4 = *reinterpret_cast<const f32x4*>(&flow[(size_t)(b * 2 + 1) * HW_ + hw]);

    bool ol[4];
    bool any = false;
    #pragma unroll
    for (int j = 0; j < 4; ++j) {
        ol[j] = !(fabsf(fx4[j]) <= MARGIN_ && fabsf(fy4[j]) <= MARGIN_);
        any |= ol[j];
    }
    if (!any) return;

    const float* imgb = img + (size_t)b * C_ * HW_;
    const size_t out_b = (size_t)b * C_ * Ho_ * Wo_;
    const size_t chs = (size_t)Ho_ * Wo_;
    #pragma unroll
    for (int j = 0; j < 4; ++j) {
        if (!ol[j]) continue;
        int hwj = hw + j;
        int h = hwj / W_;
        int w = hwj - h * W_;
        float x = ((float)w + fx4[j]) * (float)SCALE_;
        float y = ((float)h + fy4[j]) * (float)SCALE_;
        float x0f = floorf(x), y0f = floorf(y);
        float ax = x - x0f, ay = y - y0f;
        int ix0 = (int)x0f, iy0 = (int)y0f;
        float v0 = imgb[hwj];
        float v1 = imgb[HW_ + hwj];
        float v2 = imgb[2 * HW_ + hwj];
        float wxs[2] = {1.0f - ax, ax};
        float wys[2] = {1.0f - ay, ay};
        #pragma unroll
        for (int ky = 0; ky < 2; ++ky) {
            int yi = iy0 + ky;
            if ((unsigned)yi >= (unsigned)Ho_) continue;
            #pragma unroll
            for (int kx = 0; kx < 2; ++kx) {
                int xi = ix0 + kx;
                if ((unsigned)xi >= (unsigned)Wo_) continue;
                float wt = wxs[kx] * wys[ky];
                size_t base = out_b + (size_t)yi * Wo_ + (size_t)xi;
                atomicAdd(&out[base + 0 * chs], v0 * wt);
                atomicAdd(&out[base + 1 * chs], v1 * wt);
                atomicAdd(&out[base + 2 * chs], v2 * wt);
            }
        }
    }
}

// ---------------- fallback: naive global-atomic splat (scale != 4) ----------------
__global__ __launch_bounds__(256) void splat_naive(const float* __restrict__ img,
                                                   const float* __restrict__ flow,
                                                   const int* __restrict__ scale_p,
                                                   float* __restrict__ out) {
    int idx = blockIdx.x * blockDim.x + threadIdx.x;
    if (idx >= NPIX_) return;
    const int s = *scale_p;
    const int Ho = H_ * s, Wo = W_ * s;
    int w = idx % W_;
    int t = idx / W_;
    int h = t % H_;
    int b = t / H_;
    const int hw = h * W_ + w;
    float fx = flow[((b * 2 + 0) * H_) * W_ + hw];
    float fy = flow[((b * 2 + 1) * H_) * W_ + hw];
    float x = ((float)w + fx) * (float)s;
    float y = ((float)h + fy) * (float)s;
    float x0f = floorf(x), y0f = floorf(y);
    float ax = x - x0f, ay = y - y0f;
    int ix0 = (int)x0f, iy0 = (int)y0f;
    const size_t img_b = (size_t)b * C_ * HW_;
    float v0 = img[img_b + 0 * (size_t)HW_ + hw];
    float v1 = img[img_b + 1 * (size_t)HW_ + hw];
    float v2 = img[img_b + 2 * (size_t)HW_ + hw];
    const size_t out_b = (size_t)b * C_ * Ho * Wo;
    const size_t out_chs = (size_t)Ho * Wo;
    float wxs[2] = {1.0f - ax, ax};
    float wys[2] = {1.0f - ay, ay};
    #pragma unroll
    for (int ky = 0; ky < 2; ++ky) {
        int yi = iy0 + ky;
        if (yi < 0 || yi > Ho - 1) continue;
        #pragma unroll
        for (int kx = 0; kx < 2; ++kx) {
            int xi = ix0 + kx;
            if (xi < 0 || xi > Wo - 1) continue;
            float wt = wxs[kx] * wys[ky];
            size_t base = out_b + (size_t)yi * Wo + (size_t)xi;
            atomicAdd(&out[base + 0 * out_chs], v0 * wt);
            atomicAdd(&out[base + 1 * out_chs], v1 * wt);
            atomicAdd(&out[base + 2 * out_chs], v2 * wt);
        }
    }
}

extern "C" void kernel_launch(void* const* d_in, const int* in_sizes, int n_in,
                              void* d_out, int out_size, void* d_ws, size_t ws_size,
                              hipStream_t stream) {
    const float* img   = (const float*)d_in[0];
    const float* flow  = (const float*)d_in[1];
    const int*   scale = (const int*)d_in[2];
    float* out = (float*)d_out;

    const bool scale4 = (out_size == B_ * C_ * Ho_ * Wo_);
    const size_t need = 2048 + (size_t)NREG_ * REG_CAP_ * sizeof(unsigned);

    if (scale4 && ws_size >= need) {
        unsigned* counts  = (unsigned*)d_ws;
        unsigned* records = (unsigned*)((char*)d_ws + 2048);
        collect_kernel<<<NREG_, 256, 0, stream>>>(img, flow, counts, records);
        warp_tile_kernel<<<NTILES_, 256, 0, stream>>>(img, flow, counts, records, out);
    } else if (scale4) {
        warp_tile_kernel<<<NTILES_, 256, 0, stream>>>(img, flow, nullptr, nullptr, out);
        outlier_kernel<<<NPIX_ / 4 / 256, 256, 0, stream>>>(img, flow, out);
    } else {
        (void)hipMemsetAsync(out, 0, (size_t)out_size * sizeof(float), stream);
        splat_naive<<<(NPIX_ + 255) / 256, 256, 0, stream>>>(img, flow, scale, out);
    }
}

// Round 19
// 42.821 us; speedup vs baseline: 1.0768x; 1.0224x over previous
//
#include <hip/hip_runtime.h>
#include <hip/hip_bf16.h>

// Forward warp (bilinear splatting), direct per-tile gather-from-window.
//   img  [B=8, C=3, H=180, W=320] f32
//   flow [B=8, 2,  H=180, W=320] f32
//   scale=4 -> out [B, C, 720, 1280] f32
//
// FINAL = R14 champion (best measured: 42.9 us, 6.4x over baseline):
//   40x32 tiles, one 256-thread block each -> 15.4 KB LDS, 8 blocks/CU =
//   32 waves/CU (HW max). Window = 28 rows x 8 aligned 4-px strips
//   (rows hb-9..hb+18, cols wb-12..wb+19; superset of the margin-8 window,
//   extra columns provably fail the hit test) -> 224 strips, ONE strip per
//   thread, 5 f32x4 batched unconditional loads (single counted wait).
//   Phase order (load-bearing, verified): LDS zero -> sync -> loads ->
//   predicate+LDS atomics (padded plane stride 1284 -> channel atomics hit
//   distinct banks) -> sync -> exclusive nontemporal f32x4 write-out
//   (no output memset, no workspace). XCD-chunked block swizzle.
// Pixels with |flow| > 8 are handled by the EXACT-complement vectorized
// outlier kernel (global atomics in a separate dispatch AFTER tile stores;
// ordering requires the split). Exact for ANY input.

typedef float f32x4 __attribute__((ext_vector_type(4)));

#define B_ 8
#define C_ 3
#define H_ 180
#define W_ 320
#define HW_ (H_ * W_)
#define SCALE_ 4
#define Ho_ (H_ * SCALE_)            // 720
#define Wo_ (W_ * SCALE_)            // 1280
#define TH_ 40
#define TW_ 32
#define NTY_ (Ho_ / TH_)             // 18
#define NTX_ (Wo_ / TW_)             // 40
#define NTILES_ (B_ * NTY_ * NTX_)   // 5760 (divisible by 8 -> bijective XCD swizzle)
#define NPIX_ (B_ * H_ * W_)         // 460800

#define MARGIN_ 8.0f
#define WIN_H_ 28                    // rows hb-9 .. hb+18
#define NSTRIP_W_ 8                  // strips of 4 cols: wb-12 .. wb+19
#define NSTRIPS_ (WIN_H_ * NSTRIP_W_)  // 224 (<= 256: one strip per thread)
#define PLANE_STRIDE_ 1284           // 1280+4: channel atomics -> distinct banks, 16B-aligned
#define LDS_FLOATS_ (C_ * PLANE_STRIDE_)   // 3852 floats = 15408 B -> 8 blocks/CU (thread cap)

__global__ __launch_bounds__(256) void warp_tile_kernel(const float* __restrict__ img,
                                                        const float* __restrict__ flow,
                                                        float* __restrict__ out) {
    __shared__ __align__(16) float acc[LDS_FLOATS_];
    const int tid = threadIdx.x;

    // XCD-chunked swizzle (5760 % 8 == 0 -> bijective).
    int tile = (int)(blockIdx.x & 7) * (NTILES_ / 8) + (int)(blockIdx.x >> 3);
    const int tx = tile % NTX_;
    const int tt = tile / NTX_;
    const int ty = tt % NTY_;
    const int b  = tt / NTY_;
    const int px0 = tx * TW_;
    const int py0 = ty * TH_;

    for (int j = tid; j < LDS_FLOATS_ / 4; j += 256)
        *reinterpret_cast<f32x4*>(&acc[j * 4]) = (f32x4)(0.f);
    __syncthreads();

    const float* __restrict__ fxp  = flow + (size_t)(b * 2 + 0) * HW_;
    const float* __restrict__ fyp  = flow + (size_t)(b * 2 + 1) * HW_;
    const float* __restrict__ imgb = img + (size_t)b * C_ * HW_;

    const int hb = py0 >> 2;   // 10*ty
    const int wb = px0 >> 2;   // 8*tx (multiple of 8 -> strips 4-aligned)

    // ---- phase 1: one aligned 4-px strip per thread, 5 f32x4 batched loads ----
    const int r  = tid / NSTRIP_W_;
    const int s  = tid - r * NSTRIP_W_;
    const int h  = hb - 9 + r;
    const int w0 = wb - 12 + 4 * s;
    // strip fully in-row or fully out (w0 % 4 == 0, W % 4 == 0)
    const bool act = (tid < NSTRIPS_) &&
                     ((unsigned)h < (unsigned)H_) && ((unsigned)w0 < (unsigned)W_);
    const int hw = act ? (h * W_ + w0) : 0;
    f32x4 fx4 = *reinterpret_cast<const f32x4*>(&fxp[hw]);
    f32x4 fy4 = *reinterpret_cast<const f32x4*>(&fyp[hw]);
    f32x4 v04 = *reinterpret_cast<const f32x4*>(&imgb[hw]);
    f32x4 v14 = *reinterpret_cast<const f32x4*>(&imgb[HW_ + hw]);
    f32x4 v24 = *reinterpret_cast<const f32x4*>(&imgb[2 * HW_ + hw]);

    // ---- phase 2: predicate + hit-test + LDS accumulate ----
    if (act) {
        #pragma unroll
        for (int j = 0; j < 4; ++j) {
            float fx = fx4[j], fy = fy4[j];
            // Must be the EXACT complement of outlier_kernel's predicate.
            if (!(fabsf(fx) <= MARGIN_ && fabsf(fy) <= MARGIN_)) continue;

            float x = ((float)(w0 + j) + fx) * (float)SCALE_;
            float y = ((float)h + fy) * (float)SCALE_;
            float x0f = floorf(x), y0f = floorf(y);
            int ix0 = (int)x0f - px0;   // tile-local
            int iy0 = (int)y0f - py0;
            bool cx0 = (unsigned)ix0 < (unsigned)TW_;
            bool cx1 = (unsigned)(ix0 + 1) < (unsigned)TW_;
            bool cy0 = (unsigned)iy0 < (unsigned)TH_;
            bool cy1 = (unsigned)(iy0 + 1) < (unsigned)TH_;
            if (!((cx0 | cx1) & (cy0 | cy1))) continue;

            float ax = x - x0f, ay = y - y0f;
            float wxs[2] = {1.0f - ax, ax};
            float wys[2] = {1.0f - ay, ay};
            bool cxs[2] = {cx0, cx1};
            bool cys[2] = {cy0, cy1};
            float v0 = v04[j], v1 = v14[j], v2 = v24[j];
            #pragma unroll
            for (int ky = 0; ky < 2; ++ky) {
                if (!cys[ky]) continue;
                #pragma unroll
                for (int kx = 0; kx < 2; ++kx) {
                    if (!cxs[kx]) continue;
                    float wt = wxs[kx] * wys[ky];
                    int la = (iy0 + ky) * TW_ + (ix0 + kx);
                    atomicAdd(&acc[la], v0 * wt);
                    atomicAdd(&acc[la + PLANE_STRIDE_], v1 * wt);
                    atomicAdd(&acc[la + 2 * PLANE_STRIDE_], v2 * wt);
                }
            }
        }
    }
    __syncthreads();

    // ---- phase 3: exclusive coalesced nontemporal float4 write-out ----
    const size_t outb = (size_t)b * C_ * Ho_ * Wo_;
    const size_t chs  = (size_t)Ho_ * Wo_;
    const int F4_PER_PLANE = TH_ * TW_ / 4;        // 320
    const int F4_PER_ROW   = TW_ / 4;              // 8
    #pragma unroll
    for (int j = tid; j < C_ * F4_PER_PLANE; j += 256) {   // 960 total, <=4 iters
        int ch  = j / F4_PER_PLANE;
        int rem = j - ch * F4_PER_PLANE;
        int yy  = rem / F4_PER_ROW;
        int xx4 = rem - yy * F4_PER_ROW;
        f32x4 v = *reinterpret_cast<const f32x4*>(&acc[ch * PLANE_STRIDE_ + yy * TW_ + xx4 * 4]);
        __builtin_nontemporal_store(v,
            reinterpret_cast<f32x4*>(
                &out[outb + (size_t)ch * chs + (size_t)(py0 + yy) * Wo_ + px0 + xx4 * 4]));
    }
}

// Pixels with |flow| > MARGIN_: exact global-atomic splat (AFTER tile writes).
// Vectorized: 4 px/thread via f32x4 flow loads; fast path = all inliers.
__global__ __launch_bounds__(256) void outlier_kernel(const float* __restrict__ img,
                                                      const float* __restrict__ flow,
                                                      float* __restrict__ out) {
    int q = blockIdx.x * 256 + threadIdx.x;   // grid exactly NPIX_/4/256 = 450
    int idx = q * 4;
    int b = idx / HW_;                         // HW_ % 4 == 0 -> same b for all 4
    int hw = idx - b * HW_;
    f32x4 fx4 = *reinterpret_cast<const f32x4*>(&flow[(size_t)(b * 2 + 0) * HW_ + hw]);
    f32x4 fy4 = *reinterpret_cast<const f32x4*>(&flow[(size_t)(b * 2 + 1) * HW_ + hw]);

    bool ol[4];
    bool any = false;
    #pragma unroll
    for (int j = 0; j < 4; ++j) {
        ol[j] = !(fabsf(fx4[j]) <= MARGIN_ && fabsf(fy4[j]) <= MARGIN_);
        any |= ol[j];
    }
    if (!any) return;

    const float* imgb = img + (size_t)b * C_ * HW_;
    const size_t out_b = (size_t)b * C_ * Ho_ * Wo_;
    const size_t chs = (size_t)Ho_ * Wo_;
    #pragma unroll
    for (int j = 0; j < 4; ++j) {
        if (!ol[j]) continue;
        int hwj = hw + j;
        int h = hwj / W_;
        int w = hwj - h * W_;
        float x = ((float)w + fx4[j]) * (float)SCALE_;
        float y = ((float)h + fy4[j]) * (float)SCALE_;
        float x0f = floorf(x), y0f = floorf(y);
        float ax = x - x0f, ay = y - y0f;
        int ix0 = (int)x0f, iy0 = (int)y0f;
        float v0 = imgb[hwj];
        float v1 = imgb[HW_ + hwj];
        float v2 = imgb[2 * HW_ + hwj];
        float wxs[2] = {1.0f - ax, ax};
        float wys[2] = {1.0f - ay, ay};
        #pragma unroll
        for (int ky = 0; ky < 2; ++ky) {
            int yi = iy0 + ky;
            if ((unsigned)yi >= (unsigned)Ho_) continue;
            #pragma unroll
            for (int kx = 0; kx < 2; ++kx) {
                int xi = ix0 + kx;
                if ((unsigned)xi >= (unsigned)Wo_) continue;
                float wt = wxs[kx] * wys[ky];
                size_t base = out_b + (size_t)yi * Wo_ + (size_t)xi;
                atomicAdd(&out[base + 0 * chs], v0 * wt);
                atomicAdd(&out[base + 1 * chs], v1 * wt);
                atomicAdd(&out[base + 2 * chs], v2 * wt);
            }
        }
    }
}

// ---------------- fallback: naive global-atomic splat (scale != 4) ----------------
__global__ __launch_bounds__(256) void splat_naive(const float* __restrict__ img,
                                                   const float* __restrict__ flow,
                                                   const int* __restrict__ scale_p,
                                                   float* __restrict__ out) {
    int idx = blockIdx.x * blockDim.x + threadIdx.x;
    if (idx >= NPIX_) return;
    const int s = *scale_p;
    const int Ho = H_ * s, Wo = W_ * s;
    int w = idx % W_;
    int t = idx / W_;
    int h = t % H_;
    int b = t / H_;
    const int hw = h * W_ + w;
    float fx = flow[((b * 2 + 0) * H_) * W_ + hw];
    float fy = flow[((b * 2 + 1) * H_) * W_ + hw];
    float x = ((float)w + fx) * (float)s;
    float y = ((float)h + fy) * (float)s;
    float x0f = floorf(x), y0f = floorf(y);
    float ax = x - x0f, ay = y - y0f;
    int ix0 = (int)x0f, iy0 = (int)y0f;
    const size_t img_b = (size_t)b * C_ * HW_;
    float v0 = img[img_b + 0 * (size_t)HW_ + hw];
    float v1 = img[img_b + 1 * (size_t)HW_ + hw];
    float v2 = img[img_b + 2 * (size_t)HW_ + hw];
    const size_t out_b = (size_t)b * C_ * Ho * Wo;
    const size_t out_chs = (size_t)Ho * Wo;
    float wxs[2] = {1.0f - ax, ax};
    float wys[2] = {1.0f - ay, ay};
    #pragma unroll
    for (int ky = 0; ky < 2; ++ky) {
        int yi = iy0 + ky;
        if (yi < 0 || yi > Ho - 1) continue;
        #pragma unroll
        for (int kx = 0; kx < 2; ++kx) {
            int xi = ix0 + kx;
            if (xi < 0 || xi > Wo - 1) continue;
            float wt = wxs[kx] * wys[ky];
            size_t base = out_b + (size_t)yi * Wo + (size_t)xi;
            atomicAdd(&out[base + 0 * out_chs], v0 * wt);
            atomicAdd(&out[base + 1 * out_chs], v1 * wt);
            atomicAdd(&out[base + 2 * out_chs], v2 * wt);
        }
    }
}

extern "C" void kernel_launch(void* const* d_in, const int* in_sizes, int n_in,
                              void* d_out, int out_size, void* d_ws, size_t ws_size,
                              hipStream_t stream) {
    const float* img   = (const float*)d_in[0];
    const float* flow  = (const float*)d_in[1];
    const int*   scale = (const int*)d_in[2];
    float* out = (float*)d_out;

    const bool scale4 = (out_size == B_ * C_ * Ho_ * Wo_);

    if (scale4) {
        warp_tile_kernel<<<NTILES_, 256, 0, stream>>>(img, flow, out);
        outlier_kernel<<<NPIX_ / 4 / 256, 256, 0, stream>>>(img, flow, out);
    } else {
        (void)hipMemsetAsync(out, 0, (size_t)out_size * sizeof(float), stream);
        splat_naive<<<(NPIX_ + 255) / 256, 256, 0, stream>>>(img, flow, scale, out);
    }
}